// Round 16
// baseline (234.711 us; speedup 1.0000x reference)
//
#include <hip/hip_runtime.h>
#include <cstdint>
#include <math.h>

#define TT 2048
#define CC 1024
#define HH 16
#define DH 64
#define BB 4
#define MM 8192   // B*T

typedef unsigned short u16;
typedef __bf16 bf16_t;
typedef bf16_t bf16x8 __attribute__((ext_vector_type(8)));
typedef float f32x4 __attribute__((ext_vector_type(4)));

// fp32 -> bf16 round-to-nearest-even (scalar)
static __device__ inline u16 f2bf(float f) {
    unsigned int u = __builtin_bit_cast(unsigned int, f);
    unsigned int lsb = (u >> 16) & 1u;
    u += 0x7fffu + lsb;
    return (u16)(u >> 16);
}

// packed 2xfp32 -> 2xbf16 (gfx950 v_cvt_pk_bf16_f32, RNE)
static __device__ inline unsigned int cvt_pk_bf16(float a, float b) {
    unsigned int r;
    asm volatile("v_cvt_pk_bf16_f32 %0, %1, %2" : "=v"(r) : "v"(a), "v"(b));
    return r;
}

// async 16B global->LDS (LDS dest wave-uniform + lane*16B)
#define GLL16(gptr, lptr)                                                            \
    __builtin_amdgcn_global_load_lds(                                                \
        (__attribute__((address_space(1))) void*)(gptr),                             \
        (__attribute__((address_space(3))) void*)(lptr), 16, 0, 0)

// ---------------- fused prep kernel (r18-verified) ----------------
__global__ void __launch_bounds__(256)
prep_kernel(const float* __restrict__ x, u16* __restrict__ xb,
            const float* __restrict__ Wq, u16* __restrict__ wqt,
            const float* __restrict__ Wo, u16* __restrict__ wot) {
    const int bid = blockIdx.x;
    if (bid < 8192) {                       // cast x
        int i = bid * 256 + threadIdx.x;
        float4 v = ((const float4*)x)[i];
        uint2 o;
        o.x = cvt_pk_bf16(v.x, v.y);
        o.y = cvt_pk_bf16(v.z, v.w);
        ((uint2*)xb)[i] = o;
        return;
    }
    __shared__ u16 tile[32 * 34];
    const float* W; u16* Wt; int N, n0, k0;
    if (bid < 8192 + 3072) {                // W_qkv
        int idx = bid - 8192;
        W = Wq; Wt = wqt; N = 3 * CC;
        n0 = (idx % 96) * 32; k0 = (idx / 96) * 32;
    } else {                                // W_out
        int idx = bid - 11264;
        W = Wo; Wt = wot; N = CC;
        n0 = (idx % 32) * 32; k0 = (idx / 32) * 32;
    }
    const int tx = threadIdx.x & 31;
    const int ty = threadIdx.x >> 5;
#pragma unroll
    for (int i = 0; i < 4; ++i) {
        int k = ty + i * 8;
        tile[tx * 34 + k] = f2bf(W[(size_t)(k0 + k) * N + n0 + tx]);
    }
    __syncthreads();
    const int tx2 = threadIdx.x & 15;
    const int ty2 = threadIdx.x >> 4;
#pragma unroll
    for (int i = 0; i < 2; ++i) {
        int r = ty2 + i * 16;
        *(unsigned int*)&Wt[(size_t)(n0 + r) * CC + k0 + 2 * tx2] =
            *(unsigned int*)&tile[r * 34 + 2 * tx2];
    }
}

// ---------------- GEMM: C[M,N] = A[M,K] @ Bt[N,K]^T + bias ----------------
// FINAL (r14-verified best): 2-phase 128x128, GLL16 double-buffer, LDS XOR
// swizzle (bank-conflicts 6.29M -> 0, r8), XCD-chunked blockIdx swizzle
// (FETCH -20%, r14). Structural plateau notes: r9 (3-buf counted vmcnt),
// r11 (coarse 8-phase 256^2) and r15 (faithful 8-phase, 2 barriers/phase,
// counted-vmcnt ledger, setprio) all landed at/below this kernel's 74us —
// the 2-phase ceiling (~680-700 TF, m230/m248 class) held against every
// HIP-source schedule restructure attempted this session.
// MODE 0: A is y in [B,H,T,Dh] bf16; write fp32 C.
// MODE 1: A row-major [M,K] bf16; qkv scatter epilogue (V^T key-permuted
//   for the attn zero-LDS-P path; Q scale+log2e folded).
template <int MODE>
__global__ void __launch_bounds__(256)
gemm_bt_kernel(const u16* __restrict__ A, const u16* __restrict__ Bt,
               const float* __restrict__ bias, float* __restrict__ Cout,
               u16* __restrict__ qws, u16* __restrict__ kws, u16* __restrict__ vtws,
               int Mdim, int Ndim, int Kdim) {
    __shared__ u16 As[2][128 * 32];
    __shared__ u16 Bs[2][128 * 32];

    const int tid  = threadIdx.x;
    const int w    = tid >> 6;
    const int lane = tid & 63;
    const int l15  = lane & 15;
    const int quad = lane >> 4;
    const int wm   = (w & 1) * 64;
    const int wn   = (w >> 1) * 64;

    // XCD-chunked swizzle: XCD j (= bid%8 by round-robin dispatch) processes
    // the contiguous tile range [j*nwg/8, (j+1)*nwg/8). Bijective (nwg%8==0).
    const int nwg = gridDim.x * gridDim.y;
    const int bid = blockIdx.y * gridDim.x + blockIdx.x;
    const int swz = (bid & 7) * (nwg >> 3) + (bid >> 3);
    const int m0  = (swz / gridDim.x) * 128;
    const int n0  = (swz % gridDim.x) * 128;

    const int row0  = tid >> 2;
    const int row1  = row0 + 64;
    const int colsw = (((tid & 3) ^ ((row0 >> 1) & 3))) << 3;

    f32x4 acc[4][4];
#pragma unroll
    for (int i = 0; i < 4; ++i)
#pragma unroll
        for (int j = 0; j < 4; ++j) acc[i][j] = (f32x4){0.f, 0.f, 0.f, 0.f};

    auto stageA = [&](int buf, int kc) {
        if (MODE == 0) {
            int kcc = kc + colsw, h = kcc >> 6, d = kcc & 63;
            int m = m0 + row0, b = m >> 11, t = m & 2047;
            GLL16(&A[(((size_t)(b * HH + h) * TT + t) * DH) + d], &As[buf][tid * 8]);
            m = m0 + row1; b = m >> 11; t = m & 2047;
            GLL16(&A[(((size_t)(b * HH + h) * TT + t) * DH) + d], &As[buf][(tid + 256) * 8]);
        } else {
            GLL16(&A[(size_t)(m0 + row0) * Kdim + kc + colsw], &As[buf][tid * 8]);
            GLL16(&A[(size_t)(m0 + row1) * Kdim + kc + colsw], &As[buf][(tid + 256) * 8]);
        }
    };

    stageA(0, 0);
    GLL16(&Bt[(size_t)(n0 + row0) * Kdim + colsw], &Bs[0][tid * 8]);
    GLL16(&Bt[(size_t)(n0 + row1) * Kdim + colsw], &Bs[0][(tid + 256) * 8]);

    const int csw = (quad ^ ((l15 >> 1) & 3)) * 8;

    const int nsteps = Kdim >> 5;
    for (int it = 0; it < nsteps; ++it) {
        const int buf = it & 1;
        __syncthreads();

        if (it + 1 < nsteps) {
            const int nbuf = buf ^ 1;
            const int kc = (it + 1) << 5;
            stageA(nbuf, kc);
            GLL16(&Bt[(size_t)(n0 + row0) * Kdim + kc + colsw], &Bs[nbuf][tid * 8]);
            GLL16(&Bt[(size_t)(n0 + row1) * Kdim + kc + colsw], &Bs[nbuf][(tid + 256) * 8]);
        }

        bf16x8 af[4], bfm[4];
#pragma unroll
        for (int mt = 0; mt < 4; ++mt)
            af[mt] = *(const bf16x8*)&As[buf][(wm + mt * 16 + l15) * 32 + csw];
#pragma unroll
        for (int nt = 0; nt < 4; ++nt)
            bfm[nt] = *(const bf16x8*)&Bs[buf][(wn + nt * 16 + l15) * 32 + csw];
#pragma unroll
        for (int mt = 0; mt < 4; ++mt)
#pragma unroll
            for (int nt = 0; nt < 4; ++nt)
                acc[mt][nt] = __builtin_amdgcn_mfma_f32_16x16x32_bf16(
                    af[mt], bfm[nt], acc[mt][nt], 0, 0, 0);
    }

#pragma unroll
    for (int mt = 0; mt < 4; ++mt) {
        int mrow_base = m0 + wm + mt * 16 + quad * 4;
#pragma unroll
        for (int nt = 0; nt < 4; ++nt) {
            int ncol = n0 + wn + nt * 16 + l15;
            float bv = bias[ncol];
            if (MODE == 0) {
#pragma unroll
                for (int r = 0; r < 4; ++r)
                    Cout[(size_t)(mrow_base + r) * Ndim + ncol] = acc[mt][nt][r] + bv;
            } else {
                int which = ncol >> 10, c = ncol & 1023;
                int h = c >> 6, d = c & 63;
                if (which == 2) {
                    int b = mrow_base >> 11, t = mrow_base & 2047;
                    int bh = b * HH + h;
                    int ch = (t >> 2) & 15;
                    int chp = (ch & 8) | (((ch >> 1) & 1) << 2) | ((ch & 1) << 1) | ((ch >> 2) & 1);
                    int tp = (t & ~63) | (chp << 2);
                    uint2 pv;
                    pv.x = cvt_pk_bf16(acc[mt][nt][0] + bv, acc[mt][nt][1] + bv);
                    pv.y = cvt_pk_bf16(acc[mt][nt][2] + bv, acc[mt][nt][3] + bv);
                    *(uint2*)&vtws[((size_t)bh * DH + d) * TT + tp] = pv;
                } else {
#pragma unroll
                    for (int r = 0; r < 4; ++r) {
                        int mrow = mrow_base + r;
                        int b = mrow >> 11, t = mrow & 2047;
                        int bh = b * HH + h;
                        float val = acc[mt][nt][r] + bv;
                        if (which == 0) {
                            qws[((size_t)bh * TT + t) * DH + d] = f2bf(val * 0.18033688f);
                        } else {
                            kws[((size_t)bh * TT + t) * DH + d] = f2bf(val);
                        }
                    }
                }
            }
        }
    }
}

// ---------------- flash attention v11: zero-LDS P path (r7-r10/r14 verified) ----------------
// Chain per tile: barrier -> K/V b128 reads -> QK MFMA -> mask/exp2/cvt_pk ->
// PV MFMA. P never touches LDS: PV contraction-slot <-> key bijection is
// matched by the GEMM's pre-permuted V^T layout, so the PV B-operand is the
// lane's own packed QK output. (256,3): arch+acc register total fits the
// ~170 cap; (256,4) spills (r6/r13 — unified VGPR+AGPR budget exceeded).
__global__ void __launch_bounds__(256, 3)
attn_kernel(const u16* __restrict__ qws, const u16* __restrict__ kws,
            const u16* __restrict__ vtws, u16* __restrict__ yws) {
    __shared__ u16 Ks[2][64 * 68];
    __shared__ u16 Vs[2][64 * 68];

    const int tid  = threadIdx.x;
    const int w    = tid >> 6;
    const int lane = tid & 63;
    const int l15  = lane & 15;
    const int quad = lane >> 4;
    const int bh   = blockIdx.x;
    const int qt   = 15 - blockIdx.y;

    const u16* Kbase = kws + (size_t)bh * TT * DH;
    const u16* Vbase = vtws + (size_t)bh * DH * TT;

    const int srow  = tid >> 2;
    const int sc16  = (tid & 3) << 4;

    bf16x8 aones;
#pragma unroll
    for (int i = 0; i < 8; ++i) aones[i] = __builtin_bit_cast(bf16_t, (u16)0x3F80);

    const int q0     = qt * 128;
    const int qr0    = q0 + w * 32;
    const int ntiles = (q0 + 128) >> 6;

    const u16* Qp = qws + ((size_t)bh * TT + qr0) * DH;
    bf16x8 bqa[2], bqb[2];
#pragma unroll
    for (int kk = 0; kk < 2; ++kk) {
        bqa[kk] = *(const bf16x8*)&Qp[l15 * DH + kk * 32 + quad * 8];
        bqb[kk] = *(const bf16x8*)&Qp[(16 + l15) * DH + kk * 32 + quad * 8];
    }

    f32x4 o[2][4], ol[2];
#pragma unroll
    for (int qg = 0; qg < 2; ++qg) {
#pragma unroll
        for (int dt = 0; dt < 4; ++dt) o[qg][dt] = (f32x4){0.f, 0.f, 0.f, 0.f};
        ol[qg] = (f32x4){0.f, 0.f, 0.f, 0.f};
    }

    uint4 pk0 = *(const uint4*)&Kbase[(size_t)srow * DH + sc16];
    uint4 pk1 = *(const uint4*)&Kbase[(size_t)srow * DH + sc16 + 8];
    uint4 pv0 = *(const uint4*)&Vbase[(size_t)srow * TT + sc16];
    uint4 pv1 = *(const uint4*)&Vbase[(size_t)srow * TT + sc16 + 8];
    *(uint4*)&Ks[0][srow * 68 + sc16]     = pk0;
    *(uint4*)&Ks[0][srow * 68 + sc16 + 8] = pk1;
    *(uint4*)&Vs[0][srow * 68 + sc16]     = pv0;
    *(uint4*)&Vs[0][srow * 68 + sc16 + 8] = pv1;
    if (ntiles > 1) {
        pk0 = *(const uint4*)&Kbase[(size_t)(64 + srow) * DH + sc16];
        pk1 = *(const uint4*)&Kbase[(size_t)(64 + srow) * DH + sc16 + 8];
        pv0 = *(const uint4*)&Vbase[(size_t)srow * TT + 64 + sc16];
        pv1 = *(const uint4*)&Vbase[(size_t)srow * TT + 64 + sc16 + 8];
    }

    for (int it = 0; it < ntiles; ++it) {
        const int buf = it & 1;
        __syncthreads();

        if (it + 1 < ntiles) {
            *(uint4*)&Ks[buf ^ 1][srow * 68 + sc16]     = pk0;
            *(uint4*)&Ks[buf ^ 1][srow * 68 + sc16 + 8] = pk1;
            *(uint4*)&Vs[buf ^ 1][srow * 68 + sc16]     = pv0;
            *(uint4*)&Vs[buf ^ 1][srow * 68 + sc16 + 8] = pv1;
            if (it + 2 < ntiles) {
                int jn = (it + 2) << 6;
                pk0 = *(const uint4*)&Kbase[(size_t)(jn + srow) * DH + sc16];
                pk1 = *(const uint4*)&Kbase[(size_t)(jn + srow) * DH + sc16 + 8];
                pv0 = *(const uint4*)&Vbase[(size_t)srow * TT + jn + sc16];
                pv1 = *(const uint4*)&Vbase[(size_t)srow * TT + jn + sc16 + 8];
            }
        }

        const int j0 = it << 6;
        if (j0 > qr0 + 31) continue;

        bf16x8 ak[8];
#pragma unroll
        for (int kk = 0; kk < 2; ++kk)
#pragma unroll
            for (int kt = 0; kt < 4; ++kt)
                ak[kk * 4 + kt] =
                    *(const bf16x8*)&Ks[buf][(kt * 16 + l15) * 68 + kk * 32 + quad * 8];

        bf16x8 avr[8];
#pragma unroll
        for (int kk = 0; kk < 2; ++kk)
#pragma unroll
            for (int dt = 0; dt < 4; ++dt)
                avr[kk * 4 + dt] =
                    *(const bf16x8*)&Vs[buf][(dt * 16 + l15) * 68 + kk * 32 + quad * 8];

        f32x4 sa[4], sb[4];
#pragma unroll
        for (int kt = 0; kt < 4; ++kt) {
            sa[kt] = (f32x4){0.f, 0.f, 0.f, 0.f};
            sb[kt] = (f32x4){0.f, 0.f, 0.f, 0.f};
        }
#pragma unroll
        for (int kk = 0; kk < 2; ++kk)
#pragma unroll
            for (int kt = 0; kt < 4; ++kt)
                sa[kt] = __builtin_amdgcn_mfma_f32_16x16x32_bf16(ak[kk * 4 + kt], bqa[kk], sa[kt], 0, 0, 0);
#pragma unroll
        for (int kk = 0; kk < 2; ++kk)
#pragma unroll
            for (int kt = 0; kt < 4; ++kt)
                sb[kt] = __builtin_amdgcn_mfma_f32_16x16x32_bf16(ak[kk * 4 + kt], bqb[kk], sb[kt], 0, 0, 0);

        if (j0 + 63 > qr0) {
            int qy0 = qr0 + l15;
            int qy1 = qr0 + 16 + l15;
#pragma unroll
            for (int kt = 0; kt < 4; ++kt)
#pragma unroll
                for (int r = 0; r < 4; ++r) {
                    int key = j0 + kt * 16 + quad * 4 + r;
                    if (key > qy0) sa[kt][r] = -INFINITY;
                    if (key > qy1) sb[kt][r] = -INFINITY;
                }
        }

#pragma unroll
        for (int kt = 0; kt < 4; ++kt)
#pragma unroll
            for (int r = 0; r < 4; ++r) {
                sa[kt][r] = __builtin_amdgcn_exp2f(sa[kt][r]);
                sb[kt][r] = __builtin_amdgcn_exp2f(sb[kt][r]);
            }

        uint4 ua0, ua1, ub0, ub1;
        ua0.x = cvt_pk_bf16(sa[0][0], sa[0][1]);
        ua0.y = cvt_pk_bf16(sa[0][2], sa[0][3]);
        ua0.z = cvt_pk_bf16(sa[1][0], sa[1][1]);
        ua0.w = cvt_pk_bf16(sa[1][2], sa[1][3]);
        ua1.x = cvt_pk_bf16(sa[2][0], sa[2][1]);
        ua1.y = cvt_pk_bf16(sa[2][2], sa[2][3]);
        ua1.z = cvt_pk_bf16(sa[3][0], sa[3][1]);
        ua1.w = cvt_pk_bf16(sa[3][2], sa[3][3]);
        ub0.x = cvt_pk_bf16(sb[0][0], sb[0][1]);
        ub0.y = cvt_pk_bf16(sb[0][2], sb[0][3]);
        ub0.z = cvt_pk_bf16(sb[1][0], sb[1][1]);
        ub0.w = cvt_pk_bf16(sb[1][2], sb[1][3]);
        ub1.x = cvt_pk_bf16(sb[2][0], sb[2][1]);
        ub1.y = cvt_pk_bf16(sb[2][2], sb[2][3]);
        ub1.z = cvt_pk_bf16(sb[3][0], sb[3][1]);
        ub1.w = cvt_pk_bf16(sb[3][2], sb[3][3]);
        bf16x8 bpa0 = __builtin_bit_cast(bf16x8, ua0);
        bf16x8 bpa1 = __builtin_bit_cast(bf16x8, ua1);
        bf16x8 bpb0 = __builtin_bit_cast(bf16x8, ub0);
        bf16x8 bpb1 = __builtin_bit_cast(bf16x8, ub1);

#pragma unroll
        for (int dt = 0; dt < 4; ++dt)
            o[0][dt] = __builtin_amdgcn_mfma_f32_16x16x32_bf16(avr[dt], bpa0, o[0][dt], 0, 0, 0);
        ol[0] = __builtin_amdgcn_mfma_f32_16x16x32_bf16(aones, bpa0, ol[0], 0, 0, 0);
#pragma unroll
        for (int dt = 0; dt < 4; ++dt)
            o[0][dt] = __builtin_amdgcn_mfma_f32_16x16x32_bf16(avr[4 + dt], bpa1, o[0][dt], 0, 0, 0);
        ol[0] = __builtin_amdgcn_mfma_f32_16x16x32_bf16(aones, bpa1, ol[0], 0, 0, 0);
#pragma unroll
        for (int dt = 0; dt < 4; ++dt)
            o[1][dt] = __builtin_amdgcn_mfma_f32_16x16x32_bf16(avr[dt], bpb0, o[1][dt], 0, 0, 0);
        ol[1] = __builtin_amdgcn_mfma_f32_16x16x32_bf16(aones, bpb0, ol[1], 0, 0, 0);
#pragma unroll
        for (int dt = 0; dt < 4; ++dt)
            o[1][dt] = __builtin_amdgcn_mfma_f32_16x16x32_bf16(avr[4 + dt], bpb1, o[1][dt], 0, 0, 0);
        ol[1] = __builtin_amdgcn_mfma_f32_16x16x32_bf16(aones, bpb1, ol[1], 0, 0, 0);
    }

#pragma unroll
    for (int qg = 0; qg < 2; ++qg) {
        float rinv = __builtin_amdgcn_rcpf(ol[qg][0]);
        int t = qr0 + qg * 16 + l15;
#pragma unroll
        for (int dt = 0; dt < 4; ++dt) {
            uint2 yv;
            yv.x = cvt_pk_bf16(o[qg][dt][0] * rinv, o[qg][dt][1] * rinv);
            yv.y = cvt_pk_bf16(o[qg][dt][2] * rinv, o[qg][dt][3] * rinv);
            *(uint2*)&yws[((size_t)bh * TT + t) * DH + dt * 16 + quad * 4] = yv;
        }
    }
}

// ---------------- launch ----------------

extern "C" void kernel_launch(void* const* d_in, const int* in_sizes, int n_in,
                              void* d_out, int out_size, void* d_ws, size_t ws_size,
                              hipStream_t stream) {
    const float* x     = (const float*)d_in[0];
    const float* W_qkv = (const float*)d_in[1];
    const float* b_qkv = (const float*)d_in[2];
    const float* W_out = (const float*)d_in[3];
    const float* b_out = (const float*)d_in[4];
    float* out = (float*)d_out;

    char* ws = (char*)d_ws;
    u16* xb   = (u16*)ws; ws += (size_t)MM * CC * 2;       // x bf16        16 MB
    u16* wqt  = (u16*)ws; ws += (size_t)3 * CC * CC * 2;   // W_qkv^T bf16   6 MB
    u16* wot  = (u16*)ws; ws += (size_t)CC * CC * 2;       // W_out^T bf16   2 MB
    u16* qws  = (u16*)ws; ws += (size_t)MM * CC * 2;       // Q [B,H,T,Dh]  16 MB
    u16* kws  = (u16*)ws; ws += (size_t)MM * CC * 2;       // K [B,H,T,Dh]  16 MB
    u16* vtws = (u16*)ws; ws += (size_t)MM * CC * 2;       // V^T (key-permuted) 16 MB
    u16* yws  = (u16*)ws; ws += (size_t)MM * CC * 2;       // y [B,H,T,Dh]  16 MB

    prep_kernel<<<8192 + 3072 + 1024, 256, 0, stream>>>(x, xb, W_qkv, wqt, W_out, wot);

    gemm_bt_kernel<1><<<dim3(24, 64), 256, 0, stream>>>(
        xb, wqt, b_qkv, nullptr, qws, kws, vtws, MM, 3 * CC, CC);

    attn_kernel<<<dim3(BB * HH, 16), 256, 0, stream>>>(qws, kws, vtws, yws);

    gemm_bt_kernel<0><<<dim3(8, 64), 256, 0, stream>>>(
        yws, wot, b_out, out, nullptr, nullptr, nullptr, MM, CC, CC);
}